// Round 1
// 146.416 us; speedup vs baseline: 1.0054x; 1.0054x over previous
//
#include <hip/hip_runtime.h>

#define CUTOFF_F 6.0f
#define PI_F 3.14159265358979323846f
#define CAP 112     // bucket capacity per dest; mean ~61, max ~96 with this fixed input
#define EXCAP 8192  // extras list capacity (overflow fallback; statistically never used)

typedef __fp16 fp16x2 __attribute__((ext_vector_type(2)));

__device__ __forceinline__ unsigned pk2(float a, float b) {
  union { fp16x2 h; unsigned u; } cv;
  cv.h = __builtin_amdgcn_cvt_pkrtz(a, b);   // v_cvt_pkrtz_f16_f32
  return cv.u;
}
__device__ __forceinline__ float f16bits(unsigned v) {
  union { unsigned short u; __fp16 h; } cv; cv.u = (unsigned short)v; return (float)cv.h;
}

template<int CTRL>
__device__ __forceinline__ float dpp_add(float x) {
  int y = __builtin_amdgcn_update_dpp(0, __float_as_int(x), CTRL, 0xf, 0xf, true);
  return x + __int_as_float(y);
}
// Sum across 64 lanes; result valid in lane 63 only. Pure VALU (DPP), no LDS.
__device__ __forceinline__ float wave_sum63(float x) {
  x = dpp_add<0x111>(x);  // row_shr:1
  x = dpp_add<0x112>(x);  // row_shr:2
  x = dpp_add<0x114>(x);  // row_shr:4
  x = dpp_add<0x118>(x);  // row_shr:8
  x = dpp_add<0x142>(x);  // row_bcast:15
  x = dpp_add<0x143>(x);  // row_bcast:31 -> lane63 = total
  return x;
}
// Sum across each 16-lane row; result valid in in-row lane 15 only.
__device__ __forceinline__ float row_sum15(float x) {
  x = dpp_add<0x111>(x);  // row_shr:1
  x = dpp_add<0x112>(x);  // row_shr:2
  x = dpp_add<0x114>(x);  // row_shr:4
  x = dpp_add<0x118>(x);  // row_shr:8 -> lane15(+16k) = row total
  return x;
}

__device__ __forceinline__ float fast_tanh(float x) {
  float e = __expf(2.0f * x);
  return 1.0f - 2.0f * __builtin_amdgcn_rcpf(e + 1.0f);
}

// Replaces hipMemsetAsync: the rocclr fill kernel runs at ~6.6 GB/s (measured
// R7: 268 MB poison = 40.7 ms). Zeroing 64 KB + 4 B ourselves costs ~3 us.
__global__ __launch_bounds__(256) void field_zero(
    int* __restrict__ counts, int* __restrict__ ecount, int bn) {
  const int i = blockIdx.x * 256 + threadIdx.x;
  if (i < bn) counts[i] = 0;
  if (i == 0) ecount[0] = 0;
}

__global__ __launch_bounds__(256) void field_main(
    const int* __restrict__ element_map,
    const int* __restrict__ neighbor_indices,
    const int* __restrict__ neighbor_types,
    const float4* __restrict__ neighbor_vectors,
    const float* __restrict__ type_embed,
    const float* __restrict__ elem_bias,
    const float* __restrict__ W1,
    const float* __restrict__ b1,
    const float* __restrict__ W2,
    const float* __restrict__ b2,
    const float* __restrict__ W3,
    const float* __restrict__ b3,
    float* __restrict__ outEi,     // [B*n]
    int* __restrict__ counts,      // ws: [B*n] (zeroed by field_zero)
    int* __restrict__ ecount,      // ws: overflow counter (zeroed)
    float4* __restrict__ extras,   // ws: [EXCAP] overflow payloads {g3/r3, dest}
    float4* __restrict__ bucket,   // ws: [B*n*CAP] payload 6xf16 {g3, r3}
    float* __restrict__ partials,  // ws: [gridDim.x*10] {vir[9], Ei_sum}
    int n)
{
  __shared__ float4 sW1t[32];       // {W1[0][k],W1[1][k],W1[2][k],W1[3][k]}
  __shared__ float  sbte[3][33];    // b1[k] + type_embed[t][k]; stride 33: bank=(t+k)%32, no 3-way conflict
  __shared__ float  sW2[32 * 33];   // padded stride 33
  __shared__ float  sW3[32];
  __shared__ float  sb2[32];
  __shared__ float  sElemBias[3];
  __shared__ float  sb3;
  __shared__ float  blkEi[4];
  __shared__ float  blkVir[4][9];
  __shared__ unsigned hb[4][64][9]; // chunked transpose buf: 8 packed dims + 1 pad
  __shared__ float    gtd[4][3][32];// per-wave rows: 0=g(mean), 1=t, 2=dg/m

  const int tid = threadIdx.x;

  // ---- cooperative LDS staging of weights ----
  if (tid < 32) {
    sW1t[tid] = make_float4(W1[tid], W1[32 + tid], W1[64 + tid], W1[96 + tid]);
    sW3[tid]  = W3[tid];
    sb2[tid]  = b2[tid];
  } else if (tid < 128) {
    int t = (tid - 32) >> 5, k = tid & 31;
    sbte[t][k] = b1[k] + type_embed[t * 32 + k];
  } else if (tid == 128) {
    sb3 = b3[0];
  } else if (tid < 132) {
    sElemBias[tid - 129] = elem_bias[tid - 129];
  }
  for (int i = tid; i < 1024; i += 256) {
    int l = i >> 5, k = i & 31;
    sW2[l * 33 + k] = W2[i];
  }
  __syncthreads();

  const int wave = tid >> 6;
  const int lane = tid & 63;
  const int atom = blockIdx.x * 4 + wave;  // [0, B*n)
  const int bb = atom / n;

  const int base = atom * 64 + lane;  // neighbor slot
  const int idx = neighbor_indices[base];
  const int dest = bb * n + idx;
  const int em = element_map[atom];   // hoisted: latency hides under the MLP

  // hoisted count atomic: return latency hides under the MLP
  int pos = 0;
  const bool real = (idx < n);
  if (real) pos = atomicAdd(&counts[dest], 1);

  const float4 nv = neighbor_vectors[base];
  const float rx = nv.y, ry = nv.z, rz = nv.w;
  const int typ = neighbor_types[base];

  // ---- s(d), s'(d) ----
  const float d2 = rx * rx + ry * ry + rz * rz;
  const float d = sqrtf(d2);
  const float invd = (d > 0.0f) ? __builtin_amdgcn_rcpf(d) : 0.0f;
  float s, sp;
  if (d < CUTOFF_F) {
    const float arg = d * (PI_F / CUTOFF_F);
    const float cs = __cosf(arg);
    const float sn = __sinf(arg);
    const float e = __expf(-d);
    const float fc = 0.5f * (cs + 1.0f);
    const float fcp = -(0.5f * PI_F / CUTOFF_F) * sn;
    s = e * fc;
    sp = e * (fcp - fc);
  } else {
    s = 0.0f;
    sp = 0.0f;
  }
  const float f1 = s * rx, f2 = s * ry, f3 = s * rz;

  // ---- forward MLP + chunked transpose: two passes of 16 dims, reusing hb ----
  float h[32];
  const int dim = lane & 15;        // transpose role: dim handled by this lane
  const int q   = lane >> 4;        //   neighbor quartile summed by this lane
  const int w   = dim >> 1;
  const int sh  = (dim & 1) << 4;

#pragma unroll
  for (int pass = 0; pass < 2; ++pass) {
    const int kb = pass << 4;       // dim base: 0 or 16
#pragma unroll
    for (int k = 0; k < 16; k += 2) {
      const float4 wa = sW1t[kb + k];
      float pa = sbte[typ][kb + k];
      pa = fmaf(s, wa.x, pa); pa = fmaf(f1, wa.y, pa);
      pa = fmaf(f2, wa.z, pa); pa = fmaf(f3, wa.w, pa);
      h[kb + k] = fast_tanh(pa);
      const float4 wb = sW1t[kb + k + 1];
      float pb = sbte[typ][kb + k + 1];
      pb = fmaf(s, wb.x, pb); pb = fmaf(f1, wb.y, pb);
      pb = fmaf(f2, wb.z, pb); pb = fmaf(f3, wb.w, pb);
      h[kb + k + 1] = fast_tanh(pb);
      hb[wave][lane][k >> 1] = pk2(h[kb + k], h[kb + k + 1]);
    }
    // transpose: lane sums its dim over its 16-neighbor quartile (2 indep chains)
    float s0 = 0.0f, s1 = 0.0f;
#pragma unroll
    for (int jj = 0; jj < 16; jj += 2) {
      s0 += f16bits(hb[wave][(q << 4) + jj][w] >> sh);
      s1 += f16bits(hb[wave][(q << 4) + jj + 1][w] >> sh);
    }
    float gs = s0 + s1;
    gs += __shfl_xor(gs, 16);       // combine quartiles
    gs += __shfl_xor(gs, 32);
    if (lane < 16) gtd[wave][0][kb + lane] = gs * (1.0f / 64.0f);
  }

  // ---- h2 (dim kd per lane; lane-halves split the 32-dot, combine via shfl) ----
  const int kd = lane & 31;
  const int lb = (lane >> 5) << 4;   // this half's k-range base: 0 or 16
  float a0 = (lane < 32) ? sb2[kd] : 0.0f;
  float a1 = 0.0f;
  {
    const float4 gA = *(const float4*)&gtd[wave][0][lb];
    const float4 gB = *(const float4*)&gtd[wave][0][lb + 4];
    const float4 gC = *(const float4*)&gtd[wave][0][lb + 8];
    const float4 gD = *(const float4*)&gtd[wave][0][lb + 12];
    a0 = fmaf(gA.x, sW2[(lb + 0) * 33 + kd], a0);
    a0 = fmaf(gA.y, sW2[(lb + 1) * 33 + kd], a0);
    a0 = fmaf(gA.z, sW2[(lb + 2) * 33 + kd], a0);
    a0 = fmaf(gA.w, sW2[(lb + 3) * 33 + kd], a0);
    a1 = fmaf(gB.x, sW2[(lb + 4) * 33 + kd], a1);
    a1 = fmaf(gB.y, sW2[(lb + 5) * 33 + kd], a1);
    a1 = fmaf(gB.z, sW2[(lb + 6) * 33 + kd], a1);
    a1 = fmaf(gB.w, sW2[(lb + 7) * 33 + kd], a1);
    a0 = fmaf(gC.x, sW2[(lb + 8) * 33 + kd], a0);
    a0 = fmaf(gC.y, sW2[(lb + 9) * 33 + kd], a0);
    a0 = fmaf(gC.z, sW2[(lb + 10) * 33 + kd], a0);
    a0 = fmaf(gC.w, sW2[(lb + 11) * 33 + kd], a0);
    a1 = fmaf(gD.x, sW2[(lb + 12) * 33 + kd], a1);
    a1 = fmaf(gD.y, sW2[(lb + 13) * 33 + kd], a1);
    a1 = fmaf(gD.z, sW2[(lb + 14) * 33 + kd], a1);
    a1 = fmaf(gD.w, sW2[(lb + 15) * 33 + kd], a1);
  }
  float acc = a0 + a1;
  acc += __shfl_xor(acc, 32);        // combine the two half-dots
  const float h2 = fast_tanh(acc);
  const float tl = (1.0f - h2 * h2) * sW3[kd];
  if (lane < 32) gtd[wave][1][kd] = tl;

  // ---- dg/m (dim kd; same half-split over the l-sum) ----
  float b0 = 0.0f, b1v = 0.0f;
  {
    const float4 tA = *(const float4*)&gtd[wave][1][lb];
    const float4 tB = *(const float4*)&gtd[wave][1][lb + 4];
    const float4 tC = *(const float4*)&gtd[wave][1][lb + 8];
    const float4 tD = *(const float4*)&gtd[wave][1][lb + 12];
    b0 = fmaf(tA.x, sW2[kd * 33 + lb + 0], b0);
    b0 = fmaf(tA.y, sW2[kd * 33 + lb + 1], b0);
    b0 = fmaf(tA.z, sW2[kd * 33 + lb + 2], b0);
    b0 = fmaf(tA.w, sW2[kd * 33 + lb + 3], b0);
    b1v = fmaf(tB.x, sW2[kd * 33 + lb + 4], b1v);
    b1v = fmaf(tB.y, sW2[kd * 33 + lb + 5], b1v);
    b1v = fmaf(tB.z, sW2[kd * 33 + lb + 6], b1v);
    b1v = fmaf(tB.w, sW2[kd * 33 + lb + 7], b1v);
    b0 = fmaf(tC.x, sW2[kd * 33 + lb + 8], b0);
    b0 = fmaf(tC.y, sW2[kd * 33 + lb + 9], b0);
    b0 = fmaf(tC.z, sW2[kd * 33 + lb + 10], b0);
    b0 = fmaf(tC.w, sW2[kd * 33 + lb + 11], b0);
    b1v = fmaf(tD.x, sW2[kd * 33 + lb + 12], b1v);
    b1v = fmaf(tD.y, sW2[kd * 33 + lb + 13], b1v);
    b1v = fmaf(tD.z, sW2[kd * 33 + lb + 14], b1v);
    b1v = fmaf(tD.w, sW2[kd * 33 + lb + 15], b1v);
  }
  float dg = b0 + b1v;
  dg += __shfl_xor(dg, 32);          // combine the two half-dots
  if (lane < 32) gtd[wave][2][kd] = dg * (1.0f / 64.0f);

  // ---- Ei partial (each dim appears twice across 64 lanes -> x0.5 later) ----
  float p = h2 * sW3[kd];

  // ---- backward to feat: 4 indep accumulator chains ----
  float q0 = 0.0f, q1 = 0.0f, q2 = 0.0f, q3 = 0.0f;
#pragma unroll
  for (int k = 0; k < 32; k += 4) {
    const float4 d4 = *(const float4*)&gtd[wave][2][k];
#pragma unroll
    for (int u = 0; u < 4; ++u) {
      const float dgk = (u == 0) ? d4.x : (u == 1) ? d4.y : (u == 2) ? d4.z : d4.w;
      const float hk = h[k + u];
      const float dpre = dgk * (1.0f - hk * hk);
      const float4 wv = sW1t[k + u];
      q0 = fmaf(dpre, wv.x, q0);
      q1 = fmaf(dpre, wv.y, q1);
      q2 = fmaf(dpre, wv.z, q2);
      q3 = fmaf(dpre, wv.w, q3);
    }
  }

  const float common = sp * invd * (q0 + q1 * rx + q2 * ry + q3 * rz);
  const float gx = fmaf(common, rx, s * q1);
  const float gy = fmaf(common, ry, s * q2);
  const float gz = fmaf(common, rz, s * q3);

  // ---- deposit payload {g3,r3} as 6xf16 in one 16B slot ----
  if (real) {
    float4 pay;
    pay.x = __uint_as_float(pk2(gx, gy));
    pay.y = __uint_as_float(pk2(gz, rx));
    pay.z = __uint_as_float(pk2(ry, rz));
    if (pos < CAP) {
      pay.w = 0.0f;
      bucket[(size_t)dest * CAP + pos] = pay;
    } else {
      // overflow fallback (never fires with this input): append to extras list
      const int ep = atomicAdd(ecount, 1);
      if (ep < EXCAP) {
        pay.w = __int_as_float(dest);
        extras[ep] = pay;
      }
    }
  }

  // ---- wave reductions via DPP: self-force, virial, Ei ----
  float sfx = wave_sum63(gx);
  float sfy = wave_sum63(gy);
  float sfz = wave_sum63(gz);
  float vr0 = wave_sum63(rx * gx), vr1 = wave_sum63(rx * gy), vr2 = wave_sum63(rx * gz);
  float vr3 = wave_sum63(ry * gx), vr4 = wave_sum63(ry * gy), vr5 = wave_sum63(ry * gz);
  float vr6 = wave_sum63(rz * gx), vr7 = wave_sum63(rz * gy), vr8 = wave_sum63(rz * gz);
  float psum = wave_sum63(p) * 0.5f;

  if (lane == 63) {
    const float Ei_val = psum + sb3 + sElemBias[em];
    outEi[atom] = Ei_val;
    blkEi[wave] = Ei_val;
    blkVir[wave][0] = vr0; blkVir[wave][1] = vr1; blkVir[wave][2] = vr2;
    blkVir[wave][3] = vr3; blkVir[wave][4] = vr4; blkVir[wave][5] = vr5;
    blkVir[wave][6] = vr6; blkVir[wave][7] = vr7; blkVir[wave][8] = vr8;
    // self-force as a bucket entry {-sf, r=0}: gather needs no read-modify-write
    float4 pay;
    pay.x = __uint_as_float(pk2(-sfx, -sfy));
    pay.y = __uint_as_float(pk2(-sfz, 0.0f));
    pay.z = 0.0f;
    const int spos = atomicAdd(&counts[atom], 1);
    if (spos < CAP) {
      pay.w = 0.0f;
      bucket[(size_t)atom * CAP + spos] = pay;
    } else {
      const int ep = atomicAdd(ecount, 1);
      if (ep < EXCAP) {
        pay.w = __int_as_float(atom);
        extras[ep] = pay;
      }
    }
  }

  __syncthreads();
  if (tid < 9) {
    partials[blockIdx.x * 10 + tid] =
        blkVir[0][tid] + blkVir[1][tid] + blkVir[2][tid] + blkVir[3][tid];
  } else if (tid == 9) {
    partials[blockIdx.x * 10 + 9] = blkEi[0] + blkEi[1] + blkEi[2] + blkEi[3];
  }
}

// 16 lanes per destination atom (16 dests per 256-block): amortizes the
// 12-value reduction over 4x more dests per wave than the old 1-dest/wave
// layout (180 -> ~49 wave-instrs per dest). Loads stay 256B-coalesced per
// 16-lane group. Blocks 0/1 also fold the Etot/virial partials reduction.
__global__ __launch_bounds__(256) void field_gather(
    const int* __restrict__ counts,
    const int* __restrict__ ecount,
    const float4* __restrict__ extras,
    const float4* __restrict__ bucket,
    const float* __restrict__ partials,
    float* __restrict__ outForce,
    float* __restrict__ outAV,
    float* __restrict__ outEtot,
    float* __restrict__ outVirial,
    int half)   // main-grid rows of partials per batch
{
  __shared__ float sf[16][12];
  __shared__ float sacc[4][10];
  const int tid = threadIdx.x;
  const int wave = tid >> 6;
  const int lane = tid & 63;
  const int grp = tid >> 4;          // 0..15: dest group within block
  const int sub = tid & 15;          // lane within group
  const int dest = blockIdx.x * 16 + grp;  // [0, B*n)

  const int rawcnt = counts[dest];
  const int cnt = (rawcnt > CAP) ? CAP : rawcnt;
  const int ec0 = *ecount;  // uniform L2-hit load; ==0 in practice

  float fx = 0.0f, fy = 0.0f, fz = 0.0f;
  float a0 = 0, a1 = 0, a2 = 0, a3 = 0, a4 = 0, a5 = 0, a6 = 0, a7 = 0, a8 = 0;

  const float4* row = bucket + (size_t)dest * CAP;
#pragma unroll 2
  for (int l = sub; l < cnt; l += 16) {
    const float4 pay = row[l];  // 16 lanes x 16B = 256B coalesced chunk
    const unsigned w0 = __float_as_uint(pay.x);
    const unsigned w1 = __float_as_uint(pay.y);
    const unsigned w2 = __float_as_uint(pay.z);
    const float gx = f16bits(w0), gy = f16bits(w0 >> 16);
    const float gz = f16bits(w1), rx = f16bits(w1 >> 16);
    const float ry = f16bits(w2), rz = f16bits(w2 >> 16);
    fx -= gx; fy -= gy; fz -= gz;
    a0 = fmaf(rx, gx, a0); a1 = fmaf(rx, gy, a1); a2 = fmaf(rx, gz, a2);
    a3 = fmaf(ry, gx, a3); a4 = fmaf(ry, gy, a4); a5 = fmaf(ry, gz, a5);
    a6 = fmaf(rz, gx, a6); a7 = fmaf(rz, gy, a7); a8 = fmaf(rz, gz, a8);
  }

  if (ec0 > 0) {  // overflow extras scan (never in practice; block-uniform branch)
    const int ec = (ec0 < EXCAP) ? ec0 : EXCAP;
    for (int t = sub; t < ec; t += 16) {
      const float4 ex = extras[t];
      if (__float_as_int(ex.w) == dest) {
        const unsigned w0 = __float_as_uint(ex.x);
        const unsigned w1 = __float_as_uint(ex.y);
        const unsigned w2 = __float_as_uint(ex.z);
        const float gx = f16bits(w0), gy = f16bits(w0 >> 16);
        const float gz = f16bits(w1), rx = f16bits(w1 >> 16);
        const float ry = f16bits(w2), rz = f16bits(w2 >> 16);
        fx -= gx; fy -= gy; fz -= gz;
        a0 = fmaf(rx, gx, a0); a1 = fmaf(rx, gy, a1); a2 = fmaf(rx, gz, a2);
        a3 = fmaf(ry, gx, a3); a4 = fmaf(ry, gy, a4); a5 = fmaf(ry, gz, a5);
        a6 = fmaf(rz, gx, a6); a7 = fmaf(rz, gy, a7); a8 = fmaf(rz, gz, a8);
      }
    }
  }

  // 16-lane row reductions; in-row lane 15 holds each group's totals
  fx = row_sum15(fx); fy = row_sum15(fy); fz = row_sum15(fz);
  a0 = row_sum15(a0); a1 = row_sum15(a1); a2 = row_sum15(a2);
  a3 = row_sum15(a3); a4 = row_sum15(a4); a5 = row_sum15(a5);
  a6 = row_sum15(a6); a7 = row_sum15(a7); a8 = row_sum15(a8);

  if (sub == 15) {
    float* o = sf[grp];
    o[0] = fx; o[1] = fy; o[2] = fz;
    o[3] = a0; o[4] = a1; o[5] = a2;
    o[6] = a3; o[7] = a4; o[8] = a5;
    o[9] = a6; o[10] = a7; o[11] = a8;
  }
  __syncthreads();

  const int d0 = blockIdx.x * 16;
  if (tid < 48) {
    outForce[(size_t)d0 * 3 + tid] = sf[tid / 3][tid % 3];      // coalesced 48-float store
  } else if (tid >= 64 && tid < 208) {
    const int t = tid - 64;                                      // t in [0,144)
    outAV[(size_t)d0 * 9 + t] = sf[t / 9][3 + t % 9];            // coalesced 144-float store
  }

  // ---- folded Etot/virial reduction (blocks 0,1; partials complete) ----
  if (blockIdx.x < 2) {
    const int b = blockIdx.x;
    float acc[10] = {0, 0, 0, 0, 0, 0, 0, 0, 0, 0};
    for (int r = b * half + tid; r < (b + 1) * half; r += 256) {
#pragma unroll
      for (int t = 0; t < 10; ++t) acc[t] += partials[r * 10 + t];
    }
#pragma unroll
    for (int t = 0; t < 10; ++t) acc[t] = wave_sum63(acc[t]);
    if (lane == 63) {
#pragma unroll
      for (int t = 0; t < 10; ++t) sacc[wave][t] = acc[t];
    }
    __syncthreads();
    if (tid < 9) {
      outVirial[b * 9 + tid] = sacc[0][tid] + sacc[1][tid] + sacc[2][tid] + sacc[3][tid];
    } else if (tid == 9) {
      outEtot[b] = sacc[0][9] + sacc[1][9] + sacc[2][9] + sacc[3][9];
    }
  }
}

extern "C" void kernel_launch(void* const* d_in, const int* in_sizes, int n_in,
                              void* d_out, int out_size, void* d_ws, size_t ws_size,
                              hipStream_t stream) {
  const int* element_map        = (const int*)d_in[0];
  const int* neighbor_indices   = (const int*)d_in[2];
  const int* neighbor_types     = (const int*)d_in[3];
  const float4* neighbor_vectors = (const float4*)d_in[4];
  const float* type_embed = (const float*)d_in[6];
  const float* elem_bias  = (const float*)d_in[7];
  const float* W1 = (const float*)d_in[8];
  const float* b1 = (const float*)d_in[9];
  const float* W2 = (const float*)d_in[10];
  const float* b2 = (const float*)d_in[11];
  const float* W3 = (const float*)d_in[12];
  const float* b3 = (const float*)d_in[13];

  const int B = 2;
  const int bn = in_sizes[0];
  const int n = bn / B;
  const int nblk = bn / 4;

  float* out = (float*)d_out;
  float* outEtot   = out;
  float* outEi     = outEtot + B;
  float* outForce  = outEi + bn;
  float* outVirial = outForce + (size_t)bn * 3;
  float* outAV     = outVirial + (size_t)B * 9;

  // ws layout: counts | ecount(16B) | extras | partials | bucket  (all 16B-multiples)
  char* ws = (char*)d_ws;
  int* counts = (int*)ws;
  size_t countBytes = (size_t)bn * sizeof(int);
  int* ecount = (int*)(ws + countBytes);
  size_t ecountBytes = 16;
  float4* extras = (float4*)(ws + countBytes + ecountBytes);
  size_t extrasBytes = (size_t)EXCAP * sizeof(float4);
  float* partials = (float*)(ws + countBytes + ecountBytes + extrasBytes);
  size_t partialBytes = (size_t)nblk * 10 * sizeof(float);
  float4* bucket = (float4*)(ws + countBytes + ecountBytes + extrasBytes + partialBytes);

  dim3 block(256);
  hipLaunchKernelGGL(field_zero, dim3((bn + 255) / 256), block, 0, stream,
                     counts, ecount, bn);
  hipLaunchKernelGGL(field_main, dim3(nblk), block, 0, stream,
                     element_map, neighbor_indices, neighbor_types,
                     neighbor_vectors, type_embed, elem_bias,
                     W1, b1, W2, b2, W3, b3,
                     outEi, counts, ecount, extras, bucket, partials, n);
  hipLaunchKernelGGL(field_gather, dim3(bn / 16), block, 0, stream,
                     counts, ecount, extras, bucket, partials,
                     outForce, outAV, outEtot, outVirial, nblk / B);
}